// Round 2
// baseline (298.599 us; speedup 1.0000x reference)
//
#include <hip/hip_runtime.h>
#include <math.h>

#define B_ 16
#define L_ 256
#define D_ 64

// fast tanh: overflow-safe, ~1e-7 rel error (threshold is 1e-2)
__device__ __forceinline__ float ftanh(float x) {
    float ax = fabsf(x);
    float e  = __expf(-2.0f * ax);                       // in (0,1]
    float r  = (1.0f - e) * __builtin_amdgcn_rcpf(1.0f + e);
    return copysignf(r, x);
}

// Conv "level" pass, vectorized: each thread computes 8 contiguous columns of
// ONE output row. Output row i reads concat rows 2i-1..2i+1: rows <64 from X
// (time t), rows >=64 from H (time t-1, zero at t==0). Level ordering
// guarantees all H rows read here were written by earlier passes.
template<int NROWS>
__global__ __launch_bounds__(256) void conv_pass2(const float* __restrict__ X,
                                                  float* __restrict__ H,
                                                  const float* __restrict__ Wl,
                                                  const float* __restrict__ bl,
                                                  int i0) {
    const int tid    = threadIdx.x;
    const int row_id = blockIdx.x * 32 + (tid >> 3);   // 32 rows per block
    const int c0     = (tid & 7) << 3;                 // 8 cols per thread
    const int i      = i0 + (row_id & (NROWS - 1));
    const int bt     = row_id / NROWS;
    const int t      = bt & (L_ - 1);
    const int b      = bt >> 8;                        // L_ == 256

    float w[9];
#pragma unroll
    for (int k = 0; k < 9; ++k) w[k] = Wl[k];
    const float bias = bl[0];

    float acc[8];
#pragma unroll
    for (int k = 0; k < 8; ++k) acc[k] = bias;

#pragma unroll
    for (int ki = 0; ki < 3; ++ki) {
        const int cr = 2 * i - 1 + ki;                 // concat row; -1 = pad
        const float* rp = X + 16;                      // safe dummy
        bool rv = false;
        if (cr >= 0) {
            if (cr < D_) {
                rp = X + ((size_t)(b * L_ + t) * D_ + cr) * D_;
                rv = true;
            } else if (t > 0) {
                rp = H + ((size_t)(b * L_ + t - 1) * D_ + (cr - D_)) * D_;
                rv = true;
            }
        }
        // g[] covers input cols c0-4 .. c0+11 (16 floats); col pads -> 0
        float4 v0 = make_float4(0.f, 0.f, 0.f, 0.f);
        float4 v1 = v0, v2 = v0, v3 = v0;
        if (rv) {
            if (c0 >= 4)  v0 = *reinterpret_cast<const float4*>(rp + c0 - 4);
            v1 = *reinterpret_cast<const float4*>(rp + c0);
            v2 = *reinterpret_cast<const float4*>(rp + c0 + 4);
            if (c0 <= 52) v3 = *reinterpret_cast<const float4*>(rp + c0 + 8);
        }
        float g[16] = {v0.x, v0.y, v0.z, v0.w, v1.x, v1.y, v1.z, v1.w,
                       v2.x, v2.y, v2.z, v2.w, v3.x, v3.y, v3.z, v3.w};
        const float wa = w[ki * 3 + 0], wb = w[ki * 3 + 1], wc = w[ki * 3 + 2];
#pragma unroll
        for (int k = 0; k < 8; ++k)
            acc[k] = fmaf(wa, g[k + 3],
                     fmaf(wb, g[k + 4],
                     fmaf(wc, g[k + 5], acc[k])));
    }

    float o[8];
#pragma unroll
    for (int k = 0; k < 8; ++k) o[k] = ftanh(acc[k]);

    float4* dst = reinterpret_cast<float4*>(
        H + ((size_t)(b * L_ + t) * D_ + i) * D_ + c0);
    dst[0] = make_float4(o[0], o[1], o[2], o[3]);
    dst[1] = make_float4(o[4], o[5], o[6], o[7]);
}

// Sequential scan for row 63, with the h_{t-1} rows 61/62 partial fused in.
// One wave (64 lanes = 64 cols) per batch. The partial terms depend only on
// prefetched data (8-deep ring buffer), keeping them off the serial chain:
//   s_t[j] = tanh(bias + sum_{kj} w[0..2]*h61_{t-1} + w[3..5]*h62_{t-1}
//                 + w6*s_{t-1}[j-1] + w7*s_{t-1}[j] + w8*s_{t-1}[j+1])
__global__ void scan63(float* __restrict__ H,
                       const float* __restrict__ Wl,
                       const float* __restrict__ bl) {
    const int b = blockIdx.x;
    const int j = threadIdx.x;                         // 0..63, one wave
    float w[9];
#pragma unroll
    for (int k = 0; k < 9; ++k) w[k] = Wl[k];
    const float bias = bl[0];

    const size_t ST = (size_t)D_ * D_;
    float* base = H + (size_t)b * L_ * ST;             // [t*ST + row*64 + col]

    // t = 0: h_{-1} == 0 -> s = tanh(bias)
    float s = ftanh(bias);
    base[63 * 64 + j] = s;

    // ring-buffer prefetch of rows 61/62 at tprev = t-1 (slot u = (t-1)&7)
    float p61[8], p62[8];
#pragma unroll
    for (int k = 0; k < 8; ++k) {
        p61[k] = base[(size_t)k * ST + 61 * 64 + j];
        p62[k] = base[(size_t)k * ST + 62 * 64 + j];
    }

    for (int t0 = 1; t0 <= 255; t0 += 8) {
#pragma unroll
        for (int u = 0; u < 8; ++u) {
            const int t = t0 + u;
            if (t > 255) break;
            const float r61 = p61[u], r62 = p62[u];
            const int tp = t + 7;                      // refill slot u
            if (tp <= 254) {
                p61[u] = base[(size_t)tp * ST + 61 * 64 + j];
                p62[u] = base[(size_t)tp * ST + 62 * 64 + j];
            }
            // partial (independent of s)
            float l1 = __shfl_up(r61, 1);   if (j == 0)  l1 = 0.f;
            float r1 = __shfl_down(r61, 1); if (j == 63) r1 = 0.f;
            float l2 = __shfl_up(r62, 1);   if (j == 0)  l2 = 0.f;
            float r2 = __shfl_down(r62, 1); if (j == 63) r2 = 0.f;
            float p = bias;
            p = fmaf(w[0], l1, p); p = fmaf(w[1], r61, p); p = fmaf(w[2], r1, p);
            p = fmaf(w[3], l2, p); p = fmaf(w[4], r62, p); p = fmaf(w[5], r2, p);
            // serial chain
            float ls = __shfl_up(s, 1);   if (j == 0)  ls = 0.f;
            float rs = __shfl_down(s, 1); if (j == 63) rs = 0.f;
            float z = p;
            z = fmaf(w[6], ls, z); z = fmaf(w[7], s, z); z = fmaf(w[8], rs, z);
            s = ftanh(z);
            base[(size_t)t * ST + 63 * 64 + j] = s;
        }
    }
}

extern "C" void kernel_launch(void* const* d_in, const int* in_sizes, int n_in,
                              void* d_out, int out_size, void* d_ws, size_t ws_size,
                              hipStream_t stream) {
    const float* x    = (const float*)d_in[0];   // (B,L,D,D)
    const float* W    = (const float*)d_in[1];   // (2,1,1,3,3)
    const float* bias = (const float*)d_in[2];   // (2,)
    float* out = (float*)d_out;                  // layer-2 hidden states
    float* h1  = (float*)d_ws;                   // layer-1 hidden states

    for (int l = 0; l < 2; ++l) {
        const float* X  = (l == 0) ? x  : h1;
        float*       H  = (l == 0) ? h1 : out;
        const float* Wl = W + l * 9;
        const float* bl = bias + l;

        // blocks = B*L*NROWS/32
        conv_pass2<32><<<4096, 256, 0, stream>>>(X, H, Wl, bl, 0);
        conv_pass2<16><<<2048, 256, 0, stream>>>(X, H, Wl, bl, 32);
        conv_pass2< 8><<<1024, 256, 0, stream>>>(X, H, Wl, bl, 48);
        conv_pass2< 4><<< 512, 256, 0, stream>>>(X, H, Wl, bl, 56);
        conv_pass2< 2><<< 256, 256, 0, stream>>>(X, H, Wl, bl, 60);
        conv_pass2< 1><<< 128, 256, 0, stream>>>(X, H, Wl, bl, 62);
        scan63<<<B_, 64, 0, stream>>>(H, Wl, bl);
    }
}

// Round 3
// 154.809 us; speedup vs baseline: 1.9288x; 1.9288x over previous
//
#include <hip/hip_runtime.h>
#include <math.h>

#define B_ 16
#define L_ 256
#define D_ 64

// fast tanh via raw v_exp_f32: overflow-safe, ~1e-7 rel error (thr 1e-2)
__device__ __forceinline__ float ftanh(float x) {
    float ax = fabsf(x);
    float e  = __builtin_amdgcn_exp2f(-2.8853900818f * ax);   // e^{-2ax}
    float r  = (1.0f - e) * __builtin_amdgcn_rcpf(1.0f + e);
    return copysignf(r, x);
}

// DPP wave shifts with zero boundary fill (bound_ctrl=1).
// shr1: lane i <- lane i-1 (lane 0 -> 0)  == __shfl_up(x,1) w/ 0 fill
// shl1: lane i <- lane i+1 (lane 63 -> 0) == __shfl_down(x,1) w/ 0 fill
__device__ __forceinline__ float dpp_shr1(float x) {
    int r = __builtin_amdgcn_update_dpp(0, __float_as_int(x), 0x138, 0xF, 0xF, true);
    return __int_as_float(r);
}
__device__ __forceinline__ float dpp_shl1(float x) {
    int r = __builtin_amdgcn_update_dpp(0, __float_as_int(x), 0x130, 0xF, 0xF, true);
    return __int_as_float(r);
}

// Conv "level" pass, vectorized: each thread computes 8 contiguous columns of
// ONE output row. Output row i reads concat rows 2i-1..2i+1: rows <64 from X
// (time t), rows >=64 from H (time t-1, zero at t==0). Level ordering
// guarantees all H rows read here were written by earlier passes.
template<int NROWS>
__global__ __launch_bounds__(256) void conv_pass2(const float* __restrict__ X,
                                                  float* __restrict__ H,
                                                  const float* __restrict__ Wl,
                                                  const float* __restrict__ bl,
                                                  int i0) {
    const int tid    = threadIdx.x;
    const int row_id = blockIdx.x * 32 + (tid >> 3);   // 32 rows per block
    const int c0     = (tid & 7) << 3;                 // 8 cols per thread
    const int i      = i0 + (row_id & (NROWS - 1));
    const int bt     = row_id / NROWS;
    const int t      = bt & (L_ - 1);
    const int b      = bt >> 8;                        // L_ == 256

    float w[9];
#pragma unroll
    for (int k = 0; k < 9; ++k) w[k] = Wl[k];
    const float bias = bl[0];

    float acc[8];
#pragma unroll
    for (int k = 0; k < 8; ++k) acc[k] = bias;

#pragma unroll
    for (int ki = 0; ki < 3; ++ki) {
        const int cr = 2 * i - 1 + ki;                 // concat row; -1 = pad
        const float* rp = X + 16;                      // safe dummy
        bool rv = false;
        if (cr >= 0) {
            if (cr < D_) {
                rp = X + ((size_t)(b * L_ + t) * D_ + cr) * D_;
                rv = true;
            } else if (t > 0) {
                rp = H + ((size_t)(b * L_ + t - 1) * D_ + (cr - D_)) * D_;
                rv = true;
            }
        }
        // g[] covers input cols c0-4 .. c0+11 (16 floats); col pads -> 0
        float4 v0 = make_float4(0.f, 0.f, 0.f, 0.f);
        float4 v1 = v0, v2 = v0, v3 = v0;
        if (rv) {
            if (c0 >= 4)  v0 = *reinterpret_cast<const float4*>(rp + c0 - 4);
            v1 = *reinterpret_cast<const float4*>(rp + c0);
            v2 = *reinterpret_cast<const float4*>(rp + c0 + 4);
            if (c0 <= 52) v3 = *reinterpret_cast<const float4*>(rp + c0 + 8);
        }
        float g[16] = {v0.x, v0.y, v0.z, v0.w, v1.x, v1.y, v1.z, v1.w,
                       v2.x, v2.y, v2.z, v2.w, v3.x, v3.y, v3.z, v3.w};
        const float wa = w[ki * 3 + 0], wb = w[ki * 3 + 1], wc = w[ki * 3 + 2];
#pragma unroll
        for (int k = 0; k < 8; ++k)
            acc[k] = fmaf(wa, g[k + 3],
                     fmaf(wb, g[k + 4],
                     fmaf(wc, g[k + 5], acc[k])));
    }

    float o[8];
#pragma unroll
    for (int k = 0; k < 8; ++k) o[k] = ftanh(acc[k]);

    float4* dst = reinterpret_cast<float4*>(
        H + ((size_t)(b * L_ + t) * D_ + i) * D_ + c0);
    dst[0] = make_float4(o[0], o[1], o[2], o[3]);
    dst[1] = make_float4(o[4], o[5], o[6], o[7]);
}

// Sequential scan for row 63, h_{t-1} rows 61/62 partial fused in.
// One wave (64 lanes = 64 cols) per batch. src/dst alias the same buffer but
// touch DISJOINT rows (reads 61,62 / writes 63), so restrict is honest — this
// lets the compiler pipeline the ring-buffer loads past the per-step stores.
#define SDEPTH 16
__global__ void scan63(float* __restrict__ dst,
                       const float* __restrict__ src,
                       const float* __restrict__ Wl,
                       const float* __restrict__ bl) {
    const int b = blockIdx.x;
    const int j = threadIdx.x;                         // 0..63, one wave
    float w[9];
#pragma unroll
    for (int k = 0; k < 9; ++k) w[k] = Wl[k];
    const float bias = bl[0];

    const size_t ST = (size_t)D_ * D_;
    const float* s61 = src + (size_t)b * L_ * ST + 61 * 64 + j;
    const float* s62 = src + (size_t)b * L_ * ST + 62 * 64 + j;
    float*       d63 = dst + (size_t)b * L_ * ST + 63 * 64 + j;

    // t = 0: h_{-1} == 0 -> s = tanh(bias)
    float s = ftanh(bias);
    d63[0] = s;

    // ring buffer: slot u holds rows 61/62 at time (t-1) for step t, u=(t-1)%16
    float p61[SDEPTH], p62[SDEPTH];
#pragma unroll
    for (int u = 0; u < SDEPTH; ++u) {
        p61[u] = s61[(size_t)u * ST];
        p62[u] = s62[(size_t)u * ST];
    }

    for (int t0 = 1; t0 < 256; t0 += SDEPTH) {
#pragma unroll
        for (int u = 0; u < SDEPTH; ++u) {
            const int t = t0 + u;                      // (t-1)%16 == u
            if (t > 255) break;
            const float r61 = p61[u], r62 = p62[u];
            int tp = t + SDEPTH - 1;                   // refill: rows at t+15
            if (tp > 255) tp = 255;                    // clamped, unconditional
            p61[u] = s61[(size_t)tp * ST];
            p62[u] = s62[(size_t)tp * ST];
            // partial (independent of the serial chain)
            float l1 = dpp_shr1(r61), q1 = dpp_shl1(r61);
            float l2 = dpp_shr1(r62), q2 = dpp_shl1(r62);
            float p = bias;
            p = fmaf(w[0], l1, p); p = fmaf(w[1], r61, p); p = fmaf(w[2], q1, p);
            p = fmaf(w[3], l2, p); p = fmaf(w[4], r62, p); p = fmaf(w[5], q2, p);
            // serial chain: 2 DPP + 3 FMA + tanh
            float ls = dpp_shr1(s), rs = dpp_shl1(s);
            float z = fmaf(w[6], ls, fmaf(w[7], s, fmaf(w[8], rs, p)));
            s = ftanh(z);
            d63[(size_t)t * ST] = s;
        }
    }
}

extern "C" void kernel_launch(void* const* d_in, const int* in_sizes, int n_in,
                              void* d_out, int out_size, void* d_ws, size_t ws_size,
                              hipStream_t stream) {
    const float* x    = (const float*)d_in[0];   // (B,L,D,D)
    const float* W    = (const float*)d_in[1];   // (2,1,1,3,3)
    const float* bias = (const float*)d_in[2];   // (2,)
    float* out = (float*)d_out;                  // layer-2 hidden states
    float* h1  = (float*)d_ws;                   // layer-1 hidden states

    for (int l = 0; l < 2; ++l) {
        const float* X  = (l == 0) ? x  : h1;
        float*       H  = (l == 0) ? h1 : out;
        const float* Wl = W + l * 9;
        const float* bl = bias + l;

        // blocks = B*L*NROWS/32
        conv_pass2<32><<<4096, 256, 0, stream>>>(X, H, Wl, bl, 0);
        conv_pass2<16><<<2048, 256, 0, stream>>>(X, H, Wl, bl, 32);
        conv_pass2< 8><<<1024, 256, 0, stream>>>(X, H, Wl, bl, 48);
        conv_pass2< 4><<< 512, 256, 0, stream>>>(X, H, Wl, bl, 56);
        conv_pass2< 2><<< 256, 256, 0, stream>>>(X, H, Wl, bl, 60);
        conv_pass2< 1><<< 128, 256, 0, stream>>>(X, H, Wl, bl, 62);
        scan63<<<B_, 64, 0, stream>>>(H, H, Wl, bias + l);
    }
}